// Round 4
// baseline (198.037 us; speedup 1.0000x reference)
//
#include <hip/hip_runtime.h>
#include <hip/hip_bf16.h>

#define NV 100       // n_vars
#define HID 64       // hidden
#define NE 1000      // experts
#define NB 4096      // batch
#define LDW 72       // u16 stride of one w2bf row [v][h] (64 + 8 pad)
#define ESPLIT 32    // K-split count

typedef __attribute__((ext_vector_type(8))) short short8;   // MFMA A/B frag
typedef __attribute__((ext_vector_type(4))) float f32x4;    // MFMA C/D frag

__device__ __align__(16) float g_bsum[NV];

__device__ __forceinline__ unsigned short f2bf(float f) {
    union { float f; unsigned u; } v; v.f = f;
    unsigned r = v.u + 0x7fffu + ((v.u >> 16) & 1u);   // RNE (prepass/fallback only)
    return (unsigned short)(r >> 16);
}
__device__ __forceinline__ float bf2f(unsigned short s) {
    union { unsigned u; float f; } v; v.u = ((unsigned)s) << 16;
    return v.f;
}
__device__ __forceinline__ unsigned pkbf(float a, float b) {
    return (unsigned)f2bf(a) | ((unsigned)f2bf(b) << 16);
}
// hot-path convert: native __bf16 -> v_cvt_pk_bf16_f32 pairs (gfx950)
__device__ __forceinline__ short cvtbf(float f) {
    return __builtin_bit_cast(short, (__bf16)f);
}

// balanced, 4-aligned expert split: 26 splits of 32, 6 splits of 28
__device__ __host__ __forceinline__ void esplit_range(int ks, int* pe0, int* pne) {
    int e0 = (ks < 26) ? 32 * ks : 832 + 28 * (ks - 26);
    int ne = (ks < 26) ? 32 : 28;
    *pe0 = e0; *pne = ne;
}

// ---------------- bias: g_bsum[v] = sum_e b2[e*NV + v] ----------------
__global__ void bias_kernel(const float* __restrict__ b2) {
    int v = blockIdx.x;
    float s = 0.f;
    for (int e = threadIdx.x; e < NE; e += 256)
        s += b2[e * NV + v];
    __shared__ float red[4];
    for (int off = 32; off; off >>= 1) s += __shfl_down(s, off, 64);
    if ((threadIdx.x & 63) == 0) red[threadIdx.x >> 6] = s;
    __syncthreads();
    if (threadIdx.x == 0) g_bsum[v] = red[0] + red[1] + red[2] + red[3];
}

// ---------------- init: out = bsum broadcast (atomic target base) ----------------
__global__ void init_kernel(float* __restrict__ out) {
    int idx = blockIdx.x * 256 + threadIdx.x;
    if (idx < NB * NV) out[idx] = g_bsum[idx % NV];
}

// ---------------- prepass: coalesced W2 -> bf16 [e][v][LDW] via LDS transpose ----------------
__global__ void prepass2(const float* __restrict__ W2, unsigned* __restrict__ w2bf) {
    __shared__ float t[HID][NV + 1];
    int e = blockIdx.x;
    const float* src = W2 + (size_t)e * (HID * NV);
    for (int i = threadIdx.x; i < HID * NV; i += 256) {
        int hh = i / NV;
        int v = i - hh * NV;
        t[hh][v] = src[i];
    }
    __syncthreads();
    unsigned* dst = w2bf + (size_t)e * 4096;
    for (int o = threadIdx.x; o < 4096; o += 256) {
        int v = o / 36;
        int c = o - v * 36;
        unsigned val = 0;
        if (v < NV && c < 32)
            val = pkbf(t[2 * c][v], t[2 * c + 1][v]);
        dst[o] = val;
    }
}

// ---------------- main: BM=256, 8 waves as 4M x 2N, dbuf W2, atomic epilogue ----------------
__global__ __launch_bounds__(512, 4) void moe3(
    const float* __restrict__ x, const float* __restrict__ W1,
    const float* __restrict__ b1, const unsigned* __restrict__ w2bf,
    float* __restrict__ out)
{
    __shared__ __align__(16) unsigned char smem[65536];
    // [0,32768): W2 dbuf 2x16KB bf16 [v][LDW]
    unsigned short* xts = (unsigned short*)(smem + 32768);   // [32][256] bf16 x^T
    float* w1l = (float*)(smem + 49152);                     // [32][64] f32
    float* b1l = (float*)(smem + 57344);                     // [32][64] f32

    const int bid = blockIdx.x;
    const int xcd = bid & 7;
    const int jj  = bid >> 3;              // 0..63
    const int ks  = xcd * 4 + (jj & 3);    // 4 consecutive ksplits per XCD (L2 locality)
    const int mb  = jj >> 2;               // 0..15

    const int tid  = threadIdx.x;
    const int lane = tid & 63;
    const int wave = tid >> 6;             // 0..7
    const int lrow = lane & 15;
    const int kg   = lane >> 4;
    const int wm   = wave & 3;             // M group: 64 rows each
    const int wn   = wave >> 2;            // N group: tiles 0..3 / 4..6

    const int row0 = mb * 256;
    int e0, ne; esplit_range(ks, &e0, &ne);

    // ---- stage x tile: x[row0+r][e0+eb] -> xts[eb][r] bf16 (coalesced float4 reads) ----
    {
        const int r = tid >> 1;
        const int h = tid & 1;
        const float* xp = x + (size_t)(row0 + r) * NE + e0;
        #pragma unroll
        for (int c4 = 0; c4 < 4; ++c4) {
            int eb = h * 16 + c4 * 4;
            if (eb < ne) {
                float4 v = *(const float4*)(xp + eb);
                xts[(eb + 0) * 256 + r] = f2bf(v.x);
                xts[(eb + 1) * 256 + r] = f2bf(v.y);
                xts[(eb + 2) * 256 + r] = f2bf(v.z);
                xts[(eb + 3) * 256 + r] = f2bf(v.w);
            }
        }
    }
    // ---- stage W1/b1 as f32 (no unpack in hot loop) ----
    {
        int e = tid >> 4;
        int h = (tid & 15) * 4;
        if (e < ne) {
            *(float4*)&w1l[e * 64 + h] = *(const float4*)(W1 + (size_t)(e0 + e) * HID + h);
            *(float4*)&b1l[e * 64 + h] = *(const float4*)(b1 + (size_t)(e0 + e) * HID + h);
        }
    }

    auto stage_w2 = [&](int buf, int e) {
        const unsigned* g = w2bf + (size_t)e * 4096;
        unsigned* lbase = (unsigned*)(smem + buf * 16384);
        #pragma unroll
        for (int k = 0; k < 2; ++k) {
            int off16 = k * 512 + tid;
            __builtin_amdgcn_global_load_lds(
                (const __attribute__((address_space(1))) unsigned*)(g + off16 * 4),
                (__attribute__((address_space(3))) unsigned*)(lbase + off16 * 4),
                16, 0, 0);
        }
    };

    stage_w2(0, e0);
    __syncthreads();   // drains vmcnt(0)+lgkmcnt(0): buf0 + x + w1/b1 ready

    f32x4 acc[4][4];   // [rf][tt]; wn==1 uses tt 0..2
    #pragma unroll
    for (int rf = 0; rf < 4; ++rf)
        #pragma unroll
        for (int tt = 0; tt < 4; ++tt)
            acc[rf][tt] = (f32x4){0.f, 0.f, 0.f, 0.f};

    int cur = 0;
    for (int ei = 0; ei < ne; ++ei) {
        if (ei + 1 < ne) stage_w2(cur ^ 1, e0 + ei + 1);   // prefetch next expert

        float xv[4];
        #pragma unroll
        for (int rf = 0; rf < 4; ++rf)
            xv[rf] = bf2f(xts[ei * 256 + wm * 64 + rf * 16 + lrow]);

        const unsigned short* w2c = (const unsigned short*)(smem + cur * 16384);

        #pragma unroll
        for (int ksh = 0; ksh < 2; ++ksh) {
            const int hb = ksh * 32 + kg * 8;
            float4 wa = *(const float4*)&w1l[ei * 64 + hb];
            float4 wb = *(const float4*)&w1l[ei * 64 + hb + 4];
            float4 ba = *(const float4*)&b1l[ei * 64 + hb];
            float4 bb = *(const float4*)&b1l[ei * 64 + hb + 4];

            short8 afr[4];
            #pragma unroll
            for (int rf = 0; rf < 4; ++rf) {
                float xr = xv[rf];
                short8 a;
                a[0] = cvtbf(fmaxf(fmaf(xr, wa.x, ba.x), 0.f));
                a[1] = cvtbf(fmaxf(fmaf(xr, wa.y, ba.y), 0.f));
                a[2] = cvtbf(fmaxf(fmaf(xr, wa.z, ba.z), 0.f));
                a[3] = cvtbf(fmaxf(fmaf(xr, wa.w, ba.w), 0.f));
                a[4] = cvtbf(fmaxf(fmaf(xr, wb.x, bb.x), 0.f));
                a[5] = cvtbf(fmaxf(fmaf(xr, wb.y, bb.y), 0.f));
                a[6] = cvtbf(fmaxf(fmaf(xr, wb.z, bb.z), 0.f));
                a[7] = cvtbf(fmaxf(fmaf(xr, wb.w, bb.w), 0.f));
                afr[rf] = a;
            }

            if (wn == 0) {
                #pragma unroll
                for (int tt = 0; tt < 4; ++tt) {
                    short8 bf = *(const short8*)&w2c[(tt * 16 + lrow) * LDW + hb];
                    #pragma unroll
                    for (int rf = 0; rf < 4; ++rf)
                        acc[rf][tt] = __builtin_amdgcn_mfma_f32_16x16x32_bf16(afr[rf], bf, acc[rf][tt], 0, 0, 0);
                }
            } else {
                #pragma unroll
                for (int tt = 0; tt < 3; ++tt) {
                    short8 bf = *(const short8*)&w2c[((tt + 4) * 16 + lrow) * LDW + hb];
                    #pragma unroll
                    for (int rf = 0; rf < 4; ++rf)
                        acc[rf][tt] = __builtin_amdgcn_mfma_f32_16x16x32_bf16(afr[rf], bf, acc[rf][tt], 0, 0, 0);
                }
            }
        }
        __syncthreads();   // next buffer landed during compute
        cur ^= 1;
    }

    // ---- epilogue: atomicAdd into bias-initialized out ----
    // C/D layout: col = lane&15, row = kg*4 + reg
    const int rowb = row0 + wm * 64 + kg * 4;
    if (wn == 0) {
        #pragma unroll
        for (int rf = 0; rf < 4; ++rf) {
            #pragma unroll
            for (int tt = 0; tt < 4; ++tt) {
                int col = tt * 16 + lrow;          // <= 63 < NV
                size_t base = (size_t)(rowb + rf * 16) * NV + col;
                #pragma unroll
                for (int r = 0; r < 4; ++r)
                    atomicAdd(&out[base + (size_t)r * NV], acc[rf][tt][r]);
            }
        }
    } else {
        #pragma unroll
        for (int rf = 0; rf < 4; ++rf) {
            #pragma unroll
            for (int tt = 0; tt < 3; ++tt) {
                int col = (tt + 4) * 16 + lrow;
                if (col < NV) {
                    size_t base = (size_t)(rowb + rf * 16) * NV + col;
                    #pragma unroll
                    for (int r = 0; r < 4; ++r)
                        atomicAdd(&out[base + (size_t)r * NV], acc[rf][tt][r]);
                }
            }
        }
    }
}

// ---------------- fallback (tiny ws): in-kernel convert + atomics ----------------
__global__ __launch_bounds__(256, 3) void moe_fallback(
    const float* __restrict__ x, const float* __restrict__ W1,
    const float* __restrict__ b1, const float* __restrict__ W2,
    float* __restrict__ dst)
{
    __shared__ unsigned short w2t[8192];
    const int tid  = threadIdx.x;
    const int lane = tid & 63;
    const int wave = tid >> 6;
    const int lrow = lane & 15;
    const int kg   = lane >> 4;
    const int row0 = blockIdx.x * 128 + wave * 32;
    const int e0 = blockIdx.y * 32;
    const int e1 = min(NE, e0 + 32);

    f32x4 acc[2][7];
    #pragma unroll
    for (int rf = 0; rf < 2; ++rf)
        #pragma unroll
        for (int t = 0; t < 7; ++t)
            acc[rf][t] = (f32x4){0.f, 0.f, 0.f, 0.f};

    const float* xr0 = x + (size_t)(row0 + lrow) * NE;
    const float* xr1 = x + (size_t)(row0 + 16 + lrow) * NE;

    for (int e = e0; e < e1; ++e) {
        __syncthreads();
        const float* src = W2 + (size_t)e * (HID * NV);
        unsigned* w2t32 = (unsigned*)w2t;
        #pragma unroll
        for (int k = 0; k < 13; ++k) {
            int i = tid + k * 256;
            if (i < (HID / 2) * NV) {
                int a3  = i / 400;
                int rem = i - a3 * 400;
                int bv  = rem >> 2;
                int c   = rem & 3;
                int hh2 = a3 * 4 + c;
                float f0 = src[(2 * hh2) * NV + bv];
                float f1 = src[(2 * hh2 + 1) * NV + bv];
                w2t32[bv * (LDW / 2) + hh2] = pkbf(f0, f1);
            }
        }
        __syncthreads();

        float xv0 = xr0[e];
        float xv1 = xr1[e];
        const float* w1p = W1 + e * HID;
        const float* b1p = b1 + e * HID;
        #pragma unroll
        for (int ksh = 0; ksh < 2; ++ksh) {
            const int hb = ksh * 32 + kg * 8;
            f32x4 w1lo = *(const f32x4*)(w1p + hb);
            f32x4 w1hi = *(const f32x4*)(w1p + hb + 4);
            f32x4 blo  = *(const f32x4*)(b1p + hb);
            f32x4 bhi  = *(const f32x4*)(b1p + hb + 4);
            short8 a0, a1;
            #pragma unroll
            for (int j = 0; j < 4; ++j) {
                a0[j]     = cvtbf(fmaxf(fmaf(xv0, w1lo[j], blo[j]), 0.f));
                a0[j + 4] = cvtbf(fmaxf(fmaf(xv0, w1hi[j], bhi[j]), 0.f));
                a1[j]     = cvtbf(fmaxf(fmaf(xv1, w1lo[j], blo[j]), 0.f));
                a1[j + 4] = cvtbf(fmaxf(fmaf(xv1, w1hi[j], bhi[j]), 0.f));
            }
            #pragma unroll
            for (int t = 0; t < 7; ++t) {
                short8 bf = *(const short8*)&w2t[(t * 16 + lrow) * LDW + hb];
                acc[0][t] = __builtin_amdgcn_mfma_f32_16x16x32_bf16(a0, bf, acc[0][t], 0, 0, 0);
                acc[1][t] = __builtin_amdgcn_mfma_f32_16x16x32_bf16(a1, bf, acc[1][t], 0, 0, 0);
            }
        }
    }

    #pragma unroll
    for (int rf = 0; rf < 2; ++rf) {
        #pragma unroll
        for (int t = 0; t < 7; ++t) {
            int col = t * 16 + lrow;
            if (col < NV) {
                size_t base = (size_t)(row0 + rf * 16 + kg * 4) * NV + col;
                #pragma unroll
                for (int r = 0; r < 4; ++r)
                    atomicAdd(&dst[base + (size_t)r * NV], acc[rf][t][r]);
            }
        }
    }
}

extern "C" void kernel_launch(void* const* d_in, const int* in_sizes, int n_in,
                              void* d_out, int out_size, void* d_ws, size_t ws_size,
                              hipStream_t stream) {
    const float* x  = (const float*)d_in[0];
    const float* W1 = (const float*)d_in[1];
    const float* b1 = (const float*)d_in[2];
    const float* W2 = (const float*)d_in[3];
    const float* b2 = (const float*)d_in[4];
    float* out = (float*)d_out;

    const size_t W2BF_BYTES = (size_t)NE * 16384;   // 16,384,000

    bias_kernel<<<NV, 256, 0, stream>>>(b2);
    init_kernel<<<(NB * NV + 255) / 256, 256, 0, stream>>>(out);

    if (ws_size >= W2BF_BYTES) {
        unsigned* w2bf = (unsigned*)d_ws;
        prepass2<<<NE, 256, 0, stream>>>(W2, w2bf);
        moe3<<<512, 512, 0, stream>>>(x, W1, b1, w2bf, out);
    } else {
        moe_fallback<<<dim3(NB / 128, ESPLIT), 256, 0, stream>>>(x, W1, b1, W2, out);
    }
}

// Round 5
// 86.438 us; speedup vs baseline: 2.2911x; 2.2911x over previous
//
#include <hip/hip_runtime.h>
#include <hip/hip_bf16.h>

#define NV 100       // n_vars
#define HID 64       // hidden
#define NE 1000      // experts
#define NB 4096      // batch
#define ESPLIT 32    // K-split count
#define W2E 3584     // u32 per expert in frag layout: 14 frags x 256 u32 (14336 B)

typedef __attribute__((ext_vector_type(8))) short short8;   // MFMA A/B frag
typedef __attribute__((ext_vector_type(4))) float f32x4;    // MFMA C/D frag

__device__ __align__(16) float g_bsum[NV];

// one-instruction RNE f32->bf16 (v_cvt path, pairs fuse to v_cvt_pk_bf16_f32)
__device__ __forceinline__ short cvtbf(float f) {
    return __builtin_bit_cast(short, (__bf16)f);
}
__device__ __forceinline__ unsigned short f2bf(float f) {
    return (unsigned short)__builtin_bit_cast(short, (__bf16)f);
}
__device__ __forceinline__ float bf2f(unsigned short s) {
    union { unsigned u; float f; } v; v.u = ((unsigned)s) << 16;
    return v.f;
}
__device__ __forceinline__ unsigned pkbf(float a, float b) {
    return (unsigned)f2bf(a) | ((unsigned)f2bf(b) << 16);
}

// balanced, 4-aligned expert split: 26 splits of 32, 6 splits of 28
__device__ __host__ __forceinline__ void esplit_range(int ks, int* pe0, int* pne) {
    int e0 = (ks < 26) ? 32 * ks : 832 + 28 * (ks - 26);
    int ne = (ks < 26) ? 32 : 28;
    *pe0 = e0; *pne = ne;
}

// ---------------- bias: g_bsum[v] = sum_e b2[e*NV + v] ----------------
__global__ void bias_kernel(const float* __restrict__ b2) {
    int v = blockIdx.x;
    float s = 0.f;
    for (int e = threadIdx.x; e < NE; e += 256)
        s += b2[e * NV + v];
    __shared__ float red[4];
    for (int off = 32; off; off >>= 1) s += __shfl_down(s, off, 64);
    if ((threadIdx.x & 63) == 0) red[threadIdx.x >> 6] = s;
    __syncthreads();
    if (threadIdx.x == 0) g_bsum[v] = red[0] + red[1] + red[2] + red[3];
}

// ---------------- init (fallback path only) ----------------
__global__ void init_kernel(float* __restrict__ out) {
    int idx = blockIdx.x * 256 + threadIdx.x;
    if (idx < NB * NV) out[idx] = g_bsum[idx % NV];
}

// ---------------- prepass: W2 [e][h][v] f32 -> frag-contiguous bf16 ----------------
// frag f = ksh*7+t (1 KiB each): u32 word at (f*256 + l*4 + q) holds
// pk(W2[h0][v], W2[h0+1][v]) with l=kg*16+lrow, h0=ksh*32+kg*8+2q, v=t*16+lrow.
// Hot-loop read becomes ds_read_b128 at f*1024 + lane*16: perfectly linear.
__global__ void prepass3(const float* __restrict__ W2, unsigned* __restrict__ w2bf) {
    __shared__ float t[HID][NV + 1];
    int e = blockIdx.x;
    const float* src = W2 + (size_t)e * (HID * NV);
    for (int i = threadIdx.x; i < HID * NV; i += 256) {
        int hh = i / NV;
        int v = i - hh * NV;
        t[hh][v] = src[i];
    }
    __syncthreads();
    unsigned* dst = w2bf + (size_t)e * W2E;
    for (int o = threadIdx.x; o < W2E; o += 256) {
        int f = o >> 8;          // 0..13
        int r = o & 255;
        int l = r >> 2;          // lane 0..63
        int q = r & 3;           // u32 word within 16B chunk
        int ksh = f / 7, tt = f - 7 * ksh;
        int kg = l >> 4, lrow = l & 15;
        int h0 = ksh * 32 + kg * 8 + 2 * q;
        int v = tt * 16 + lrow;
        unsigned val = 0;
        if (v < NV) val = pkbf(t[h0][v], t[h0 + 1][v]);
        dst[o] = val;
    }
}

// ---------------- main: BM=256, 8 waves x 32 rows, dbuf frag-layout W2 ----------------
__global__ __launch_bounds__(512, 4) void moe4(
    const float* __restrict__ x, const float* __restrict__ W1,
    const float* __restrict__ b1, const unsigned* __restrict__ w2bf,
    float* __restrict__ part)
{
    __shared__ __align__(16) unsigned char smem[61440];
    // [0, 28672): W2 dbuf 2 x 14336 B (frag layout)
    unsigned short* xts = (unsigned short*)(smem + 28672);   // [32][256] bf16 x^T
    float* w1l = (float*)(smem + 45056);                     // [32][64] f32
    float* b1l = (float*)(smem + 53248);                     // [32][64] f32

    const int bid = blockIdx.x;
    const int xcd = bid & 7;
    const int jj  = bid >> 3;              // 0..63
    const int ks  = xcd * 4 + (jj & 3);    // 4 consecutive ksplits per XCD (L2 locality)
    const int mb  = jj >> 2;               // 0..15

    const int tid  = threadIdx.x;
    const int lane = tid & 63;
    const int wave = tid >> 6;             // 0..7
    const int lrow = lane & 15;
    const int kg   = lane >> 4;

    const int row0 = mb * 256;
    int e0, ne; esplit_range(ks, &e0, &ne);

    // ---- stage x tile: x[row0+r][e0+eb] -> xts[eb][r] bf16 (coalesced float4) ----
    {
        const int r = tid >> 1;
        const int h = tid & 1;
        const float* xp = x + (size_t)(row0 + r) * NE + e0;
        #pragma unroll
        for (int c4 = 0; c4 < 4; ++c4) {
            int eb = h * 16 + c4 * 4;
            if (eb < ne) {
                float4 v = *(const float4*)(xp + eb);
                xts[(eb + 0) * 256 + r] = f2bf(v.x);
                xts[(eb + 1) * 256 + r] = f2bf(v.y);
                xts[(eb + 2) * 256 + r] = f2bf(v.z);
                xts[(eb + 3) * 256 + r] = f2bf(v.w);
            }
        }
    }
    // ---- stage W1/b1 as f32 (no unpack in hot loop) ----
    {
        int e = tid >> 4;
        int h = (tid & 15) * 4;
        if (e < ne) {
            *(float4*)&w1l[e * 64 + h] = *(const float4*)(W1 + (size_t)(e0 + e) * HID + h);
            *(float4*)&b1l[e * 64 + h] = *(const float4*)(b1 + (size_t)(e0 + e) * HID + h);
        }
    }

    // ---- W2 staging: 14336 B linear global_load_lds (896 x 16B chunks) ----
    auto stage_w2 = [&](int buf, int e) {
        const unsigned* g = w2bf + (size_t)e * W2E;
        unsigned* lbase = (unsigned*)(smem + buf * 14336);
        __builtin_amdgcn_global_load_lds(
            (const __attribute__((address_space(1))) unsigned*)(g + tid * 4),
            (__attribute__((address_space(3))) unsigned*)(lbase + tid * 4),
            16, 0, 0);
        if (tid < 384)
            __builtin_amdgcn_global_load_lds(
                (const __attribute__((address_space(1))) unsigned*)(g + (512 + tid) * 4),
                (__attribute__((address_space(3))) unsigned*)(lbase + (512 + tid) * 4),
                16, 0, 0);
    };

    stage_w2(0, e0);
    __syncthreads();   // buf0 + x + w1/b1 ready

    f32x4 acc[2][7];
    #pragma unroll
    for (int rf = 0; rf < 2; ++rf)
        #pragma unroll
        for (int t = 0; t < 7; ++t)
            acc[rf][t] = (f32x4){0.f, 0.f, 0.f, 0.f};

    const int xrow = wave * 32 + lrow;
    int cur = 0;
    for (int ei = 0; ei < ne; ++ei) {
        if (ei + 1 < ne) stage_w2(cur ^ 1, e0 + ei + 1);   // prefetch next expert

        float xv0 = bf2f(xts[ei * 256 + xrow]);
        float xv1 = bf2f(xts[ei * 256 + xrow + 16]);
        const unsigned char* w2c = smem + cur * 14336 + lane * 16;

        #pragma unroll
        for (int ksh = 0; ksh < 2; ++ksh) {
            const int hb = ksh * 32 + kg * 8;
            float4 wa = *(const float4*)&w1l[ei * 64 + hb];
            float4 wb = *(const float4*)&w1l[ei * 64 + hb + 4];
            float4 ba = *(const float4*)&b1l[ei * 64 + hb];
            float4 bb = *(const float4*)&b1l[ei * 64 + hb + 4];

            short8 a0, a1;
            a0[0] = cvtbf(fmaxf(fmaf(xv0, wa.x, ba.x), 0.f));
            a0[1] = cvtbf(fmaxf(fmaf(xv0, wa.y, ba.y), 0.f));
            a0[2] = cvtbf(fmaxf(fmaf(xv0, wa.z, ba.z), 0.f));
            a0[3] = cvtbf(fmaxf(fmaf(xv0, wa.w, ba.w), 0.f));
            a0[4] = cvtbf(fmaxf(fmaf(xv0, wb.x, bb.x), 0.f));
            a0[5] = cvtbf(fmaxf(fmaf(xv0, wb.y, bb.y), 0.f));
            a0[6] = cvtbf(fmaxf(fmaf(xv0, wb.z, bb.z), 0.f));
            a0[7] = cvtbf(fmaxf(fmaf(xv0, wb.w, bb.w), 0.f));
            a1[0] = cvtbf(fmaxf(fmaf(xv1, wa.x, ba.x), 0.f));
            a1[1] = cvtbf(fmaxf(fmaf(xv1, wa.y, ba.y), 0.f));
            a1[2] = cvtbf(fmaxf(fmaf(xv1, wa.z, ba.z), 0.f));
            a1[3] = cvtbf(fmaxf(fmaf(xv1, wa.w, ba.w), 0.f));
            a1[4] = cvtbf(fmaxf(fmaf(xv1, wb.x, bb.x), 0.f));
            a1[5] = cvtbf(fmaxf(fmaf(xv1, wb.y, bb.y), 0.f));
            a1[6] = cvtbf(fmaxf(fmaf(xv1, wb.z, bb.z), 0.f));
            a1[7] = cvtbf(fmaxf(fmaf(xv1, wb.w, bb.w), 0.f));

            #pragma unroll
            for (int t = 0; t < 7; ++t) {
                // frag-contiguous: base + (ksh*7+t)*1024 + lane*16 -> linear b128
                short8 bf = *(const short8*)(w2c + ((ksh * 7 + t) << 10));
                acc[0][t] = __builtin_amdgcn_mfma_f32_16x16x32_bf16(a0, bf, acc[0][t], 0, 0, 0);
                acc[1][t] = __builtin_amdgcn_mfma_f32_16x16x32_bf16(a1, bf, acc[1][t], 0, 0, 0);
            }
        }
        __syncthreads();   // next buffer landed during compute
        cur ^= 1;
    }

    // epilogue: C/D layout col = lane&15, row = kg*4 + reg -> partials (no atomics)
    float* dst = part + (size_t)ks * (NB * NV);
    #pragma unroll
    for (int rf = 0; rf < 2; ++rf) {
        #pragma unroll
        for (int t = 0; t < 7; ++t) {
            int col = t * 16 + lrow;
            if (col < NV) {
                size_t base = (size_t)(row0 + wave * 32 + rf * 16 + kg * 4) * NV + col;
                #pragma unroll
                for (int r = 0; r < 4; ++r)
                    dst[base + (size_t)r * NV] = acc[rf][t][r];
            }
        }
    }
}

// ---------------- reduce: out = bias + sum_k part[k] (float4) ----------------
__global__ void reduce2(const float* __restrict__ part, float* __restrict__ out) {
    int i4 = blockIdx.x * 256 + threadIdx.x;   // < NB*NV/4 = 102400
    f32x4 s = *(const f32x4*)&g_bsum[(i4 % 25) * 4];
    size_t off = (size_t)i4 * 4;
    #pragma unroll 4
    for (int k = 0; k < ESPLIT; ++k)
        s += *(const f32x4*)&part[(size_t)k * (NB * NV) + off];
    *(f32x4*)&out[off] = s;
}

// ---------------- fallback (tiny ws): in-kernel convert + atomics ----------------
#define LDW 72
__global__ __launch_bounds__(256, 3) void moe_fallback(
    const float* __restrict__ x, const float* __restrict__ W1,
    const float* __restrict__ b1, const float* __restrict__ W2,
    float* __restrict__ dst)
{
    __shared__ unsigned short w2t[8192];
    const int tid  = threadIdx.x;
    const int lane = tid & 63;
    const int wave = tid >> 6;
    const int lrow = lane & 15;
    const int kg   = lane >> 4;
    const int row0 = blockIdx.x * 128 + wave * 32;
    const int e0 = blockIdx.y * 32;
    const int e1 = min(NE, e0 + 32);

    f32x4 acc[2][7];
    #pragma unroll
    for (int rf = 0; rf < 2; ++rf)
        #pragma unroll
        for (int t = 0; t < 7; ++t)
            acc[rf][t] = (f32x4){0.f, 0.f, 0.f, 0.f};

    const float* xr0 = x + (size_t)(row0 + lrow) * NE;
    const float* xr1 = x + (size_t)(row0 + 16 + lrow) * NE;

    for (int e = e0; e < e1; ++e) {
        __syncthreads();
        const float* src = W2 + (size_t)e * (HID * NV);
        unsigned* w2t32 = (unsigned*)w2t;
        #pragma unroll
        for (int k = 0; k < 13; ++k) {
            int i = tid + k * 256;
            if (i < (HID / 2) * NV) {
                int a3  = i / 400;
                int rem = i - a3 * 400;
                int bv  = rem >> 2;
                int c   = rem & 3;
                int hh2 = a3 * 4 + c;
                float f0 = src[(2 * hh2) * NV + bv];
                float f1 = src[(2 * hh2 + 1) * NV + bv];
                w2t32[bv * (LDW / 2) + hh2] = pkbf(f0, f1);
            }
        }
        __syncthreads();

        float xv0 = xr0[e];
        float xv1 = xr1[e];
        const float* w1p = W1 + e * HID;
        const float* b1p = b1 + e * HID;
        #pragma unroll
        for (int ksh = 0; ksh < 2; ++ksh) {
            const int hb = ksh * 32 + kg * 8;
            f32x4 w1lo = *(const f32x4*)(w1p + hb);
            f32x4 w1hi = *(const f32x4*)(w1p + hb + 4);
            f32x4 blo  = *(const f32x4*)(b1p + hb);
            f32x4 bhi  = *(const f32x4*)(b1p + hb + 4);
            short8 a0, a1;
            #pragma unroll
            for (int j = 0; j < 4; ++j) {
                a0[j]     = cvtbf(fmaxf(fmaf(xv0, w1lo[j], blo[j]), 0.f));
                a0[j + 4] = cvtbf(fmaxf(fmaf(xv0, w1hi[j], bhi[j]), 0.f));
                a1[j]     = cvtbf(fmaxf(fmaf(xv1, w1lo[j], blo[j]), 0.f));
                a1[j + 4] = cvtbf(fmaxf(fmaf(xv1, w1hi[j], bhi[j]), 0.f));
            }
            #pragma unroll
            for (int t = 0; t < 7; ++t) {
                short8 bf = *(const short8*)&w2t[(t * 16 + lrow) * LDW + hb];
                acc[0][t] = __builtin_amdgcn_mfma_f32_16x16x32_bf16(a0, bf, acc[0][t], 0, 0, 0);
                acc[1][t] = __builtin_amdgcn_mfma_f32_16x16x32_bf16(a1, bf, acc[1][t], 0, 0, 0);
            }
        }
    }

    #pragma unroll
    for (int rf = 0; rf < 2; ++rf) {
        #pragma unroll
        for (int t = 0; t < 7; ++t) {
            int col = t * 16 + lrow;
            if (col < NV) {
                size_t base = (size_t)(row0 + rf * 16 + kg * 4) * NV + col;
                #pragma unroll
                for (int r = 0; r < 4; ++r)
                    atomicAdd(&dst[base + (size_t)r * NV], acc[rf][t][r]);
            }
        }
    }
}

extern "C" void kernel_launch(void* const* d_in, const int* in_sizes, int n_in,
                              void* d_out, int out_size, void* d_ws, size_t ws_size,
                              hipStream_t stream) {
    const float* x  = (const float*)d_in[0];
    const float* W1 = (const float*)d_in[1];
    const float* b1 = (const float*)d_in[2];
    const float* W2 = (const float*)d_in[3];
    const float* b2 = (const float*)d_in[4];
    float* out = (float*)d_out;

    const size_t W2BF_BYTES = (size_t)NE * W2E * 4;          // 14,336,000
    const size_t PART_BYTES = (size_t)ESPLIT * NB * NV * 4;  // 52,428,800

    bias_kernel<<<NV, 256, 0, stream>>>(b2);

    if (ws_size >= W2BF_BYTES + PART_BYTES) {
        unsigned* w2bf = (unsigned*)d_ws;
        float* part = (float*)((char*)d_ws + W2BF_BYTES);
        prepass3<<<NE, 256, 0, stream>>>(W2, w2bf);
        moe4<<<512, 512, 0, stream>>>(x, W1, b1, w2bf, part);
        reduce2<<<(NB * NV / 4 + 255) / 256, 256, 0, stream>>>(part, out);
    } else {
        init_kernel<<<(NB * NV + 255) / 256, 256, 0, stream>>>(out);
        moe_fallback<<<dim3(NB / 128, ESPLIT), 256, 0, stream>>>(x, W1, b1, W2, out);
    }
}

// Round 6
// 83.964 us; speedup vs baseline: 2.3586x; 1.0295x over previous
//
#include <hip/hip_runtime.h>
#include <hip/hip_bf16.h>

#define NV 100       // n_vars
#define HID 64       // hidden
#define NE 1000      // experts
#define NB 4096      // batch
#define ESPLIT 32    // K-split count
#define W2E 3584     // u32 per expert in frag layout: 14 frags x 256 u32 (14336 B)

typedef __attribute__((ext_vector_type(8))) short short8;   // MFMA A/B frag
typedef __attribute__((ext_vector_type(4))) float f32x4;    // MFMA C/D frag

__device__ __align__(16) float g_bsum[NV];

// one-instruction RNE f32->bf16 (v_cvt path, pairs fuse to v_cvt_pk_bf16_f32)
__device__ __forceinline__ short cvtbf(float f) {
    return __builtin_bit_cast(short, (__bf16)f);
}
__device__ __forceinline__ unsigned short f2bf(float f) {
    return (unsigned short)__builtin_bit_cast(short, (__bf16)f);
}
__device__ __forceinline__ float bf2f(unsigned short s) {
    union { unsigned u; float f; } v; v.u = ((unsigned)s) << 16;
    return v.f;
}
__device__ __forceinline__ unsigned pkbf(float a, float b) {
    return (unsigned)f2bf(a) | ((unsigned)f2bf(b) << 16);
}

// balanced, 4-aligned expert split: 26 splits of 32, 6 splits of 28
__device__ __host__ __forceinline__ void esplit_range(int ks, int* pe0, int* pne) {
    int e0 = (ks < 26) ? 32 * ks : 832 + 28 * (ks - 26);
    int ne = (ks < 26) ? 32 : 28;
    *pe0 = e0; *pne = ne;
}

// ---------------- bias: g_bsum[v] = sum_e b2[e*NV + v] ----------------
__global__ void bias_kernel(const float* __restrict__ b2) {
    int v = blockIdx.x;
    float s = 0.f;
    for (int e = threadIdx.x; e < NE; e += 256)
        s += b2[e * NV + v];
    __shared__ float red[4];
    for (int off = 32; off; off >>= 1) s += __shfl_down(s, off, 64);
    if ((threadIdx.x & 63) == 0) red[threadIdx.x >> 6] = s;
    __syncthreads();
    if (threadIdx.x == 0) g_bsum[v] = red[0] + red[1] + red[2] + red[3];
}

// ---------------- init (fallback path only) ----------------
__global__ void init_kernel(float* __restrict__ out) {
    int idx = blockIdx.x * 256 + threadIdx.x;
    if (idx < NB * NV) out[idx] = g_bsum[idx % NV];
}

// ---------------- prepass: W2 [e][h][v] f32 -> frag-contiguous bf16 ----------------
// frag f = ksh*7+t (1 KiB each): u32 word at (f*256 + l*4 + q) holds
// pk(W2[h0][v], W2[h0+1][v]) with l=kg*16+lrow, h0=ksh*32+kg*8+2q, v=t*16+lrow.
// Hot-loop read becomes ds_read_b128 at f*1024 + lane*16: perfectly linear.
__global__ void prepass3(const float* __restrict__ W2, unsigned* __restrict__ w2bf) {
    __shared__ float t[HID][NV + 1];
    int e = blockIdx.x;
    const float* src = W2 + (size_t)e * (HID * NV);
    for (int i = threadIdx.x; i < HID * NV; i += 256) {
        int hh = i / NV;
        int v = i - hh * NV;
        t[hh][v] = src[i];
    }
    __syncthreads();
    unsigned* dst = w2bf + (size_t)e * W2E;
    for (int o = threadIdx.x; o < W2E; o += 256) {
        int f = o >> 8;          // 0..13
        int r = o & 255;
        int l = r >> 2;          // lane 0..63
        int q = r & 3;           // u32 word within 16B chunk
        int ksh = f / 7, tt = f - 7 * ksh;
        int kg = l >> 4, lrow = l & 15;
        int h0 = ksh * 32 + kg * 8 + 2 * q;
        int v = tt * 16 + lrow;
        unsigned val = 0;
        if (v < NV) val = pkbf(t[h0][v], t[h0 + 1][v]);
        dst[o] = val;
    }
}

// ---------------- main: 4 waves x 64 rows (BM=256), dbuf frag-layout W2 ----------------
// Each B-fragment read feeds 4 MFMAs (4 row-frags per wave) -> LDS reads halved vs r5.
__global__ __launch_bounds__(256, 2) void moe5(
    const float* __restrict__ x, const float* __restrict__ W1,
    const float* __restrict__ b1, const unsigned* __restrict__ w2bf,
    float* __restrict__ part)
{
    __shared__ __align__(16) unsigned char smem[61440];
    // [0, 28672): W2 dbuf 2 x 14336 B (frag layout)
    unsigned short* xts = (unsigned short*)(smem + 28672);   // [32][256] bf16 x^T
    float* w1l = (float*)(smem + 45056);                     // [32][64] f32
    float* b1l = (float*)(smem + 53248);                     // [32][64] f32

    const int bid = blockIdx.x;
    const int xcd = bid & 7;
    const int jj  = bid >> 3;              // 0..63
    const int ks  = xcd * 4 + (jj & 3);    // 4 consecutive ksplits per XCD (L2 locality)
    const int mb  = jj >> 2;               // 0..15

    const int tid  = threadIdx.x;
    const int lane = tid & 63;
    const int wave = tid >> 6;             // 0..3, owns rows wave*64 .. wave*64+63
    const int lrow = lane & 15;
    const int kg   = lane >> 4;

    const int row0 = mb * 256;
    int e0, ne; esplit_range(ks, &e0, &ne);

    // ---- stage x tile: x[row0+tid][e0+eb] -> xts[eb][tid] bf16 ----
    {
        const float* xp = x + (size_t)(row0 + tid) * NE + e0;
        #pragma unroll
        for (int c4 = 0; c4 < 8; ++c4) {
            int eb = c4 * 4;
            if (eb < ne) {
                float4 v = *(const float4*)(xp + eb);
                xts[(eb + 0) * 256 + tid] = f2bf(v.x);
                xts[(eb + 1) * 256 + tid] = f2bf(v.y);
                xts[(eb + 2) * 256 + tid] = f2bf(v.z);
                xts[(eb + 3) * 256 + tid] = f2bf(v.w);
            }
        }
    }
    // ---- stage W1/b1 as f32 (coalesced: 8 consecutive floats per thread) ----
    {
        int e = tid >> 3;
        int h = (tid & 7) * 8;
        if (e < ne) {
            const float* wsrc = W1 + (size_t)(e0 + e) * HID + h;
            const float* bsrc = b1 + (size_t)(e0 + e) * HID + h;
            *(float4*)&w1l[e * 64 + h]     = *(const float4*)(wsrc);
            *(float4*)&w1l[e * 64 + h + 4] = *(const float4*)(wsrc + 4);
            *(float4*)&b1l[e * 64 + h]     = *(const float4*)(bsrc);
            *(float4*)&b1l[e * 64 + h + 4] = *(const float4*)(bsrc + 4);
        }
    }

    // ---- W2 staging: 14336 B linear global_load_lds (896 x 16B, 256 threads) ----
    auto stage_w2 = [&](int buf, int e) {
        const unsigned* g = w2bf + (size_t)e * W2E;
        unsigned* lbase = (unsigned*)(smem + buf * 14336);
        #pragma unroll
        for (int k = 0; k < 3; ++k) {
            int off16 = k * 256 + tid;
            __builtin_amdgcn_global_load_lds(
                (const __attribute__((address_space(1))) unsigned*)(g + off16 * 4),
                (__attribute__((address_space(3))) unsigned*)(lbase + off16 * 4),
                16, 0, 0);
        }
        if (tid < 128)
            __builtin_amdgcn_global_load_lds(
                (const __attribute__((address_space(1))) unsigned*)(g + (768 + tid) * 4),
                (__attribute__((address_space(3))) unsigned*)(lbase + (768 + tid) * 4),
                16, 0, 0);
    };

    stage_w2(0, e0);
    __syncthreads();   // buf0 + x + w1/b1 ready

    f32x4 acc[4][7];
    #pragma unroll
    for (int rf = 0; rf < 4; ++rf)
        #pragma unroll
        for (int t = 0; t < 7; ++t)
            acc[rf][t] = (f32x4){0.f, 0.f, 0.f, 0.f};

    int cur = 0;
    for (int ei = 0; ei < ne; ++ei) {
        if (ei + 1 < ne) stage_w2(cur ^ 1, e0 + ei + 1);   // prefetch next expert

        float xv[4];
        #pragma unroll
        for (int rf = 0; rf < 4; ++rf)
            xv[rf] = bf2f(xts[ei * 256 + wave * 64 + rf * 16 + lrow]);

        const unsigned char* w2c = smem + cur * 14336 + lane * 16;

        #pragma unroll
        for (int ksh = 0; ksh < 2; ++ksh) {
            const int hb = ksh * 32 + kg * 8;
            float4 wa = *(const float4*)&w1l[ei * 64 + hb];
            float4 wb = *(const float4*)&w1l[ei * 64 + hb + 4];
            float4 ba = *(const float4*)&b1l[ei * 64 + hb];
            float4 bb = *(const float4*)&b1l[ei * 64 + hb + 4];

            short8 afr[4];
            #pragma unroll
            for (int rf = 0; rf < 4; ++rf) {
                float xr = xv[rf];
                short8 a;
                a[0] = cvtbf(fmaxf(fmaf(xr, wa.x, ba.x), 0.f));
                a[1] = cvtbf(fmaxf(fmaf(xr, wa.y, ba.y), 0.f));
                a[2] = cvtbf(fmaxf(fmaf(xr, wa.z, ba.z), 0.f));
                a[3] = cvtbf(fmaxf(fmaf(xr, wa.w, ba.w), 0.f));
                a[4] = cvtbf(fmaxf(fmaf(xr, wb.x, bb.x), 0.f));
                a[5] = cvtbf(fmaxf(fmaf(xr, wb.y, bb.y), 0.f));
                a[6] = cvtbf(fmaxf(fmaf(xr, wb.z, bb.z), 0.f));
                a[7] = cvtbf(fmaxf(fmaf(xr, wb.w, bb.w), 0.f));
                afr[rf] = a;
            }

            #pragma unroll
            for (int t = 0; t < 7; ++t) {
                // frag-contiguous: one linear ds_read_b128 feeds 4 MFMAs
                short8 bf = *(const short8*)(w2c + ((ksh * 7 + t) << 10));
                #pragma unroll
                for (int rf = 0; rf < 4; ++rf)
                    acc[rf][t] = __builtin_amdgcn_mfma_f32_16x16x32_bf16(afr[rf], bf, acc[rf][t], 0, 0, 0);
            }
        }
        __syncthreads();   // next buffer landed during compute
        cur ^= 1;
    }

    // epilogue: C/D layout col = lane&15, row = kg*4 + reg -> partials (no atomics)
    float* dst = part + (size_t)ks * (NB * NV);
    #pragma unroll
    for (int rf = 0; rf < 4; ++rf) {
        #pragma unroll
        for (int t = 0; t < 7; ++t) {
            int col = t * 16 + lrow;
            if (col < NV) {
                size_t base = (size_t)(row0 + wave * 64 + rf * 16 + kg * 4) * NV + col;
                #pragma unroll
                for (int r = 0; r < 4; ++r)
                    dst[base + (size_t)r * NV] = acc[rf][t][r];
            }
        }
    }
}

// ---------------- reduce: out = bias + sum_k part[k] (float4) ----------------
__global__ void reduce2(const float* __restrict__ part, float* __restrict__ out) {
    int i4 = blockIdx.x * 256 + threadIdx.x;   // < NB*NV/4 = 102400
    f32x4 s = *(const f32x4*)&g_bsum[(i4 % 25) * 4];
    size_t off = (size_t)i4 * 4;
    #pragma unroll 4
    for (int k = 0; k < ESPLIT; ++k)
        s += *(const f32x4*)&part[(size_t)k * (NB * NV) + off];
    *(f32x4*)&out[off] = s;
}

// ---------------- fallback (tiny ws): in-kernel convert + atomics ----------------
#define LDW 72
__global__ __launch_bounds__(256, 3) void moe_fallback(
    const float* __restrict__ x, const float* __restrict__ W1,
    const float* __restrict__ b1, const float* __restrict__ W2,
    float* __restrict__ dst)
{
    __shared__ unsigned short w2t[8192];
    const int tid  = threadIdx.x;
    const int lane = tid & 63;
    const int wave = tid >> 6;
    const int lrow = lane & 15;
    const int kg   = lane >> 4;
    const int row0 = blockIdx.x * 128 + wave * 32;
    const int e0 = blockIdx.y * 32;
    const int e1 = min(NE, e0 + 32);

    f32x4 acc[2][7];
    #pragma unroll
    for (int rf = 0; rf < 2; ++rf)
        #pragma unroll
        for (int t = 0; t < 7; ++t)
            acc[rf][t] = (f32x4){0.f, 0.f, 0.f, 0.f};

    const float* xr0 = x + (size_t)(row0 + lrow) * NE;
    const float* xr1 = x + (size_t)(row0 + 16 + lrow) * NE;

    for (int e = e0; e < e1; ++e) {
        __syncthreads();
        const float* src = W2 + (size_t)e * (HID * NV);
        unsigned* w2t32 = (unsigned*)w2t;
        #pragma unroll
        for (int k = 0; k < 13; ++k) {
            int i = tid + k * 256;
            if (i < (HID / 2) * NV) {
                int a3  = i / 400;
                int rem = i - a3 * 400;
                int bv  = rem >> 2;
                int c   = rem & 3;
                int hh2 = a3 * 4 + c;
                float f0 = src[(2 * hh2) * NV + bv];
                float f1 = src[(2 * hh2 + 1) * NV + bv];
                w2t32[bv * (LDW / 2) + hh2] = pkbf(f0, f1);
            }
        }
        __syncthreads();

        float xv0 = xr0[e];
        float xv1 = xr1[e];
        const float* w1p = W1 + e * HID;
        const float* b1p = b1 + e * HID;
        #pragma unroll
        for (int ksh = 0; ksh < 2; ++ksh) {
            const int hb = ksh * 32 + kg * 8;
            f32x4 w1lo = *(const f32x4*)(w1p + hb);
            f32x4 w1hi = *(const f32x4*)(w1p + hb + 4);
            f32x4 blo  = *(const f32x4*)(b1p + hb);
            f32x4 bhi  = *(const f32x4*)(b1p + hb + 4);
            short8 a0, a1;
            #pragma unroll
            for (int j = 0; j < 4; ++j) {
                a0[j]     = cvtbf(fmaxf(fmaf(xv0, w1lo[j], blo[j]), 0.f));
                a0[j + 4] = cvtbf(fmaxf(fmaf(xv0, w1hi[j], bhi[j]), 0.f));
                a1[j]     = cvtbf(fmaxf(fmaf(xv1, w1lo[j], blo[j]), 0.f));
                a1[j + 4] = cvtbf(fmaxf(fmaf(xv1, w1hi[j], bhi[j]), 0.f));
            }
            #pragma unroll
            for (int t = 0; t < 7; ++t) {
                short8 bf = *(const short8*)&w2t[(t * 16 + lrow) * LDW + hb];
                acc[0][t] = __builtin_amdgcn_mfma_f32_16x16x32_bf16(a0, bf, acc[0][t], 0, 0, 0);
                acc[1][t] = __builtin_amdgcn_mfma_f32_16x16x32_bf16(a1, bf, acc[1][t], 0, 0, 0);
            }
        }
    }

    #pragma unroll
    for (int rf = 0; rf < 2; ++rf) {
        #pragma unroll
        for (int t = 0; t < 7; ++t) {
            int col = t * 16 + lrow;
            if (col < NV) {
                size_t base = (size_t)(row0 + rf * 16 + kg * 4) * NV + col;
                #pragma unroll
                for (int r = 0; r < 4; ++r)
                    atomicAdd(&dst[base + (size_t)r * NV], acc[rf][t][r]);
            }
        }
    }
}

extern "C" void kernel_launch(void* const* d_in, const int* in_sizes, int n_in,
                              void* d_out, int out_size, void* d_ws, size_t ws_size,
                              hipStream_t stream) {
    const float* x  = (const float*)d_in[0];
    const float* W1 = (const float*)d_in[1];
    const float* b1 = (const float*)d_in[2];
    const float* W2 = (const float*)d_in[3];
    const float* b2 = (const float*)d_in[4];
    float* out = (float*)d_out;

    const size_t W2BF_BYTES = (size_t)NE * W2E * 4;          // 14,336,000
    const size_t PART_BYTES = (size_t)ESPLIT * NB * NV * 4;  // 52,428,800

    bias_kernel<<<NV, 256, 0, stream>>>(b2);

    if (ws_size >= W2BF_BYTES + PART_BYTES) {
        unsigned* w2bf = (unsigned*)d_ws;
        float* part = (float*)((char*)d_ws + W2BF_BYTES);
        prepass3<<<NE, 256, 0, stream>>>(W2, w2bf);
        moe5<<<512, 256, 0, stream>>>(x, W1, b1, w2bf, part);
        reduce2<<<(NB * NV / 4 + 255) / 256, 256, 0, stream>>>(part, out);
    } else {
        init_kernel<<<(NB * NV + 255) / 256, 256, 0, stream>>>(out);
        moe_fallback<<<dim3(NB / 128, ESPLIT), 256, 0, stream>>>(x, W1, b1, W2, out);
    }
}